// Round 7
// baseline (1775.326 us; speedup 1.0000x reference)
//
#include <hip/hip_runtime.h>

// RNN scan: h_{t+1} = 0.8*h_t + 0.2*(relu(h_t @ W_rec^T + b_rec + inp_t) + rn_t)
// 128 chains -> 128 blocks x 512 threads.  MFMA engine (R6, 845us) + R7 schedule.
//
// R7: R6 pipe accounting: step 3970cy but slowest pipe only ~2000cy (LDS) ->
// ~1900cy serialization. Prime suspect: in-loop stream reloads consumed ~8
// MFMA (~120cy wall) after issue vs ~200-300cy L2 latency -> ~1000cy vmcnt
// stall/step. FIX (schedule only, split/regs unchanged):
//   1. kk7/kk8 pre-issued in the PREVIOUS epilogue (loop-carried sa/sb) --
//      the barrier's vmcnt drain lands them before slot 1.
//   2. named/LDS kk-slots interleaved BETWEEN stream consumptions: every
//      reload gets >=2-4 slots (~250-400cy wall) of issue->use lag.
//   3. pu/pn input loads moved to the epilogue (short-lived, L2-resident):
//      -11 mid-loop regs, guards against spill.
// PREDICT: dur 845 -> 620-690us, MfmaUtil 27 -> 33-40, VALUBusy 12-15.
//
// Fragment layouts (verified working in R6):
//   A: lane l holds W[rowbase + (l&15)][32kk + 8*(l>>4) + e]  (e=0..7)
//   B: lane l holds h[32kk + 8*(l>>4) + e], identical for all 16 cols
//   D: col = l&15 (all equal), row = rowbase + 4*(l>>4) + r  (r=0..3)

#define B_  128
#define T_  512
#define N_  512
#define IN_ 6

typedef _Float16 f16x8 __attribute__((ext_vector_type(8)));
typedef float    f32x4 __attribute__((ext_vector_type(4)));
typedef _Float16 h2_t  __attribute__((ext_vector_type(2)));

union U4H8 { uint4 u; f16x8 h; };
__device__ __forceinline__ f16x8 h8(uint4 v) { U4H8 c; c.u = v; return c.h; }

// 8 consecutive fp32 -> 8 packed fp16 in a uint4
__device__ __forceinline__ uint4 pack8(const float* __restrict__ p) {
    const float4 f0 = ((const float4*)p)[0];
    const float4 f1 = ((const float4*)p)[1];
    union { unsigned u[4]; h2_t h[4]; } cv;
    cv.h[0] = h2_t{(_Float16)f0.x, (_Float16)f0.y};
    cv.h[1] = h2_t{(_Float16)f0.z, (_Float16)f0.w};
    cv.h[2] = h2_t{(_Float16)f1.x, (_Float16)f1.y};
    cv.h[3] = h2_t{(_Float16)f1.z, (_Float16)f1.w};
    return uint4{cv.u[0], cv.u[1], cv.u[2], cv.u[3]};
}

// opaque redefinition: blocks rematerialization of the producing load
#define KEEP4(v) asm volatile("" : "+v"((v).x), "+v"((v).y), "+v"((v).z), "+v"((v).w))

#define MFMA(A, Bv, C) __builtin_amdgcn_mfma_f32_16x16x32_f16(h8(A), h8(Bv), (C), 0, 0, 0)

// ---- prep: W_rec cols [224,512) -> fp16 image ws[g][n] = W[n][224+8g..+8] ----
__global__ void prep_tail_kernel(const float* __restrict__ Wrec,
                                 uint4* __restrict__ ws) {
    int tid = blockIdx.x * blockDim.x + threadIdx.x;
    if (tid >= 36 * N_) return;
    int g = tid >> 9, n = tid & (N_ - 1);
    ws[(size_t)g * N_ + n] = pack8(Wrec + (size_t)n * N_ + 224 + 8 * g);
}

// streamed A-frag (kk in 7..15): lane needs W[rowA+16T][32KK + 8q .. +8]
template <bool USE_WS>
__device__ __forceinline__ uint4 sld(const uint4* __restrict__ wsb,
                                     const float* __restrict__ Wrec,
                                     int rowA, int q, int KK, int T) {
    if constexpr (USE_WS) return wsb[2048 * (KK - 7) + 16 * T];
    else return pack8(Wrec + (size_t)(rowA + 16 * T) * N_ + 32 * KK + 8 * q);
}

template <bool USE_WS>
__global__ __launch_bounds__(512)
void rnn_scan_kernel(
    const float* __restrict__ u,     // [B,T,IN]
    const float* __restrict__ unz,   // [B,T,IN]
    const float* __restrict__ rnz,   // [B,T,N]
    const float* __restrict__ Wrec,  // [N,N]
    const float* __restrict__ brec,  // [N]
    const float* __restrict__ Win,   // [N,IN]
    const uint4* __restrict__ ws,    // fp16 tail image [36][N_]
    float* __restrict__ out)         // [B,T,N]
{
    const int b    = blockIdx.x;
    const int n    = threadIdx.x;
    const int w    = n >> 6;          // wave id: output rows 64w..64w+63
    const int lane = n & 63;
    const int q    = lane >> 4;       // k-subgroup
    const int r16  = lane & 15;       // A row-within-tile

    __shared__ uint4 lw[16 * N_];                    // 131072 B  (kk=3..6)
    __shared__ __align__(16) _Float16 hbuf[2][N_];   // 2048 B
    __shared__ float pre[N_];                        // 2048 B

    const int rowA = 64 * w + r16;
    const float* wp = Wrec + (size_t)rowA * N_ + 8 * q;  // + T*8192 + K*32

    // ---- one-time: A-frags kk=0..2 as 12 NAMED uint4 (48 VGPRs) ----
    uint4 a00 = pack8(wp +     0 +  0), a01 = pack8(wp +     0 + 32), a02 = pack8(wp +     0 + 64);
    uint4 a10 = pack8(wp +  8192 +  0), a11 = pack8(wp +  8192 + 32), a12 = pack8(wp +  8192 + 64);
    uint4 a20 = pack8(wp + 16384 +  0), a21 = pack8(wp + 16384 + 32), a22 = pack8(wp + 16384 + 64);
    uint4 a30 = pack8(wp + 24576 +  0), a31 = pack8(wp + 24576 + 32), a32 = pack8(wp + 24576 + 64);
    KEEP4(a00); KEEP4(a01); KEEP4(a02); KEEP4(a10); KEEP4(a11); KEEP4(a12);
    KEEP4(a20); KEEP4(a21); KEEP4(a22); KEEP4(a30); KEEP4(a31); KEEP4(a32);

    // ---- one-time: kk=3..6 into LDS: lw[j][m] = W[m][96+8j .. +8] ----
#pragma unroll
    for (int j = 0; j < 16; ++j)
        lw[j * N_ + n] = pack8(Wrec + (size_t)n * N_ + 96 + 8 * j);

    const float win0 = Win[n * IN_ + 0], win1 = Win[n * IN_ + 1], win2 = Win[n * IN_ + 2];
    const float win3 = Win[n * IN_ + 3], win4 = Win[n * IN_ + 4], win5 = Win[n * IN_ + 5];
    const float br = brec[n];
    const float NS = 0.6324555320336759f;  // sqrt(2/alpha * sigma^2)
    float h = 0.0f;

    float* ob = out + (size_t)b * T_ * N_;
    const float* rb = rnz + (size_t)b * T_ * N_;
    const float2* ubp = (const float2*)(u   + (size_t)b * T_ * IN_);
    const float2* nbp = (const float2*)(unz + (size_t)b * T_ * IN_);

    const uint4* wsb = nullptr;
    if constexpr (USE_WS) wsb = ws + (size_t)q * N_ + 64 * w + r16;
    const int lbase = q * N_ + 64 * w + r16;   // lw read base (kk=3, T=0)
    const uint4* hb0 = (const uint4*)&hbuf[0][0];
    const uint4* hb1 = (const uint4*)&hbuf[1][0];

    hbuf[0][n] = (_Float16)0.0f;

    // inp for t=0
    float2 cu0 = ubp[0], cu1 = ubp[1], cu2 = ubp[2];
    float2 cn0 = nbp[0], cn1 = nbp[1], cn2 = nbp[2];
    float inp_c = br;
    inp_c = fmaf(win0, fmaf(NS, cn0.x, cu0.x), inp_c);
    inp_c = fmaf(win1, fmaf(NS, cn0.y, cu0.y), inp_c);
    inp_c = fmaf(win2, fmaf(NS, cn1.x, cu1.x), inp_c);
    inp_c = fmaf(win3, fmaf(NS, cn1.y, cu1.y), inp_c);
    inp_c = fmaf(win4, fmaf(NS, cn2.x, cu2.x), inp_c);
    inp_c = fmaf(win5, fmaf(NS, cn2.y, cu2.y), inp_c);
    float rn_c = rb[n];

    // pre-issue stream kk7/kk8 for t=0 (loop-carried sa/sb)
    uint4 sa0 = sld<USE_WS>(wsb, Wrec, rowA, q, 7, 0), sa1 = sld<USE_WS>(wsb, Wrec, rowA, q, 7, 1),
          sa2 = sld<USE_WS>(wsb, Wrec, rowA, q, 7, 2), sa3 = sld<USE_WS>(wsb, Wrec, rowA, q, 7, 3);
    uint4 sb0 = sld<USE_WS>(wsb, Wrec, rowA, q, 8, 0), sb1 = sld<USE_WS>(wsb, Wrec, rowA, q, 8, 1),
          sb2 = sld<USE_WS>(wsb, Wrec, rowA, q, 8, 2), sb3 = sld<USE_WS>(wsb, Wrec, rowA, q, 8, 3);
    __syncthreads();

#pragma unroll 1
    for (int t = 0; t < T_ - 1; ++t) {
        ob[(size_t)t * N_ + n] = h;   // states[t] (t=0: zeros)

        const uint4* hb = (t & 1) ? hb1 : hb0;         // B source (h_t, fp16)
        _Float16* hbw = (t & 1) ? &hbuf[0][0] : &hbuf[1][0];

        // rn prefetch (HBM, needs max lead; consumed at this epilogue)
        const float rn_n = rb[(size_t)(t + 1) * N_ + n];

        const f32x4 zz = {0.0f, 0.0f, 0.0f, 0.0f};

        // s1: named kk0
        uint4 bf0 = hb[q];
        f32x4 d0 = MFMA(a00, bf0, zz), d1 = MFMA(a10, bf0, zz),
              d2 = MFMA(a20, bf0, zz), d3 = MFMA(a30, bf0, zz);

        // s2: named kk1  (+ lw kk3 reads for s6)
        uint4 l30 = lw[lbase + 0], l31 = lw[lbase + 16], l32 = lw[lbase + 32], l33 = lw[lbase + 48];
        uint4 bf1 = hb[4 + q];
        d0 = MFMA(a01, bf1, d0); d1 = MFMA(a11, bf1, d1);
        d2 = MFMA(a21, bf1, d2); d3 = MFMA(a31, bf1, d3);

        // s3: stream kk7 (pre-issued last epilogue) -> reissue sa = kk9
        uint4 bf7 = hb[28 + q];
        d0 = MFMA(sa0, bf7, d0); d1 = MFMA(sa1, bf7, d1);
        d2 = MFMA(sa2, bf7, d2); d3 = MFMA(sa3, bf7, d3);
        sa0 = sld<USE_WS>(wsb, Wrec, rowA, q, 9, 0); sa1 = sld<USE_WS>(wsb, Wrec, rowA, q, 9, 1);
        sa2 = sld<USE_WS>(wsb, Wrec, rowA, q, 9, 2); sa3 = sld<USE_WS>(wsb, Wrec, rowA, q, 9, 3);

        // s4: named kk2
        uint4 bf2 = hb[8 + q];
        d0 = MFMA(a02, bf2, d0); d1 = MFMA(a12, bf2, d1);
        d2 = MFMA(a22, bf2, d2); d3 = MFMA(a32, bf2, d3);

        // s5: stream kk8 -> reissue sb = kk10
        uint4 bf8 = hb[32 + q];
        d0 = MFMA(sb0, bf8, d0); d1 = MFMA(sb1, bf8, d1);
        d2 = MFMA(sb2, bf8, d2); d3 = MFMA(sb3, bf8, d3);
        sb0 = sld<USE_WS>(wsb, Wrec, rowA, q, 10, 0); sb1 = sld<USE_WS>(wsb, Wrec, rowA, q, 10, 1);
        sb2 = sld<USE_WS>(wsb, Wrec, rowA, q, 10, 2); sb3 = sld<USE_WS>(wsb, Wrec, rowA, q, 10, 3);

        // s6: lw kk3 (+ lw kk4 reads for s8)
        uint4 l40 = lw[lbase + 2048], l41 = lw[lbase + 2064], l42 = lw[lbase + 2080], l43 = lw[lbase + 2096];
        uint4 bf3 = hb[12 + q];
        d0 = MFMA(l30, bf3, d0); d1 = MFMA(l31, bf3, d1);
        d2 = MFMA(l32, bf3, d2); d3 = MFMA(l33, bf3, d3);

        // s7: stream kk9 -> reissue sa = kk11
        uint4 bf9 = hb[36 + q];
        d0 = MFMA(sa0, bf9, d0); d1 = MFMA(sa1, bf9, d1);
        d2 = MFMA(sa2, bf9, d2); d3 = MFMA(sa3, bf9, d3);
        sa0 = sld<USE_WS>(wsb, Wrec, rowA, q, 11, 0); sa1 = sld<USE_WS>(wsb, Wrec, rowA, q, 11, 1);
        sa2 = sld<USE_WS>(wsb, Wrec, rowA, q, 11, 2); sa3 = sld<USE_WS>(wsb, Wrec, rowA, q, 11, 3);

        // s8: lw kk4 (+ lw kk5 reads for s10)
        uint4 l50 = lw[lbase + 4096], l51 = lw[lbase + 4112], l52 = lw[lbase + 4128], l53 = lw[lbase + 4144];
        uint4 bf4 = hb[16 + q];
        d0 = MFMA(l40, bf4, d0); d1 = MFMA(l41, bf4, d1);
        d2 = MFMA(l42, bf4, d2); d3 = MFMA(l43, bf4, d3);

        // s9: stream kk10 -> reissue sb = kk12
        uint4 bf10 = hb[40 + q];
        d0 = MFMA(sb0, bf10, d0); d1 = MFMA(sb1, bf10, d1);
        d2 = MFMA(sb2, bf10, d2); d3 = MFMA(sb3, bf10, d3);
        sb0 = sld<USE_WS>(wsb, Wrec, rowA, q, 12, 0); sb1 = sld<USE_WS>(wsb, Wrec, rowA, q, 12, 1);
        sb2 = sld<USE_WS>(wsb, Wrec, rowA, q, 12, 2); sb3 = sld<USE_WS>(wsb, Wrec, rowA, q, 12, 3);

        // s10: lw kk5 (+ lw kk6 reads for s12)
        uint4 l60 = lw[lbase + 6144], l61 = lw[lbase + 6160], l62 = lw[lbase + 6176], l63 = lw[lbase + 6192];
        uint4 bf5 = hb[20 + q];
        d0 = MFMA(l50, bf5, d0); d1 = MFMA(l51, bf5, d1);
        d2 = MFMA(l52, bf5, d2); d3 = MFMA(l53, bf5, d3);

        // s11: stream kk11 -> reissue sa = kk13
        uint4 bf11 = hb[44 + q];
        d0 = MFMA(sa0, bf11, d0); d1 = MFMA(sa1, bf11, d1);
        d2 = MFMA(sa2, bf11, d2); d3 = MFMA(sa3, bf11, d3);
        sa0 = sld<USE_WS>(wsb, Wrec, rowA, q, 13, 0); sa1 = sld<USE_WS>(wsb, Wrec, rowA, q, 13, 1);
        sa2 = sld<USE_WS>(wsb, Wrec, rowA, q, 13, 2); sa3 = sld<USE_WS>(wsb, Wrec, rowA, q, 13, 3);

        // s12: lw kk6
        uint4 bf6 = hb[24 + q];
        d0 = MFMA(l60, bf6, d0); d1 = MFMA(l61, bf6, d1);
        d2 = MFMA(l62, bf6, d2); d3 = MFMA(l63, bf6, d3);

        // s13: stream kk12 -> reissue sb = kk14
        uint4 bf12 = hb[48 + q];
        d0 = MFMA(sb0, bf12, d0); d1 = MFMA(sb1, bf12, d1);
        d2 = MFMA(sb2, bf12, d2); d3 = MFMA(sb3, bf12, d3);
        sb0 = sld<USE_WS>(wsb, Wrec, rowA, q, 14, 0); sb1 = sld<USE_WS>(wsb, Wrec, rowA, q, 14, 1);
        sb2 = sld<USE_WS>(wsb, Wrec, rowA, q, 14, 2); sb3 = sld<USE_WS>(wsb, Wrec, rowA, q, 14, 3);

        // s14: stream kk13 -> reissue sa = kk15
        uint4 bf13 = hb[52 + q];
        d0 = MFMA(sa0, bf13, d0); d1 = MFMA(sa1, bf13, d1);
        d2 = MFMA(sa2, bf13, d2); d3 = MFMA(sa3, bf13, d3);
        sa0 = sld<USE_WS>(wsb, Wrec, rowA, q, 15, 0); sa1 = sld<USE_WS>(wsb, Wrec, rowA, q, 15, 1);
        sa2 = sld<USE_WS>(wsb, Wrec, rowA, q, 15, 2); sa3 = sld<USE_WS>(wsb, Wrec, rowA, q, 15, 3);

        // s15: stream kk14
        uint4 bf14 = hb[56 + q];
        d0 = MFMA(sb0, bf14, d0); d1 = MFMA(sb1, bf14, d1);
        d2 = MFMA(sb2, bf14, d2); d3 = MFMA(sb3, bf14, d3);

        // s16: stream kk15
        uint4 bf15 = hb[60 + q];
        d0 = MFMA(sa0, bf15, d0); d1 = MFMA(sa1, bf15, d1);
        d2 = MFMA(sa2, bf15, d2); d3 = MFMA(sa3, bf15, d3);

        // ---- readout: lanes 0,16,32,48 own rows 4q..4q+3 of each tile ----
        if (r16 == 0) {
            *(f32x4*)(pre + 64 * w +  0 + 4 * q) = d0;
            *(f32x4*)(pre + 64 * w + 16 + 4 * q) = d1;
            *(f32x4*)(pre + 64 * w + 32 + 4 * q) = d2;
            *(f32x4*)(pre + 64 * w + 48 + 4 * q) = d3;
        }
        __syncthreads();

        // pre-issue next step's kk7/kk8 (sa/sb free; latency hidden by the
        // epilogue + next iteration's s1..s2)
        sa0 = sld<USE_WS>(wsb, Wrec, rowA, q, 7, 0); sa1 = sld<USE_WS>(wsb, Wrec, rowA, q, 7, 1);
        sa2 = sld<USE_WS>(wsb, Wrec, rowA, q, 7, 2); sa3 = sld<USE_WS>(wsb, Wrec, rowA, q, 7, 3);
        sb0 = sld<USE_WS>(wsb, Wrec, rowA, q, 8, 0); sb1 = sld<USE_WS>(wsb, Wrec, rowA, q, 8, 1);
        sb2 = sld<USE_WS>(wsb, Wrec, rowA, q, 8, 2); sb3 = sld<USE_WS>(wsb, Wrec, rowA, q, 8, 3);

        // t+1 inputs (L2-resident, short-lived: loaded in the epilogue only)
        const float2 pu0 = ubp[(t + 1) * 3 + 0], pu1 = ubp[(t + 1) * 3 + 1], pu2 = ubp[(t + 1) * 3 + 2];
        const float2 pn0 = nbp[(t + 1) * 3 + 0], pn1 = nbp[(t + 1) * 3 + 1], pn2 = nbp[(t + 1) * 3 + 2];

        const float prn = pre[n] + inp_c;
        h = 0.8f * h + 0.2f * (fmaxf(prn, 0.0f) + rn_c);
        hbw[n] = (_Float16)h;

        float inp_n = br;
        inp_n = fmaf(win0, fmaf(NS, pn0.x, pu0.x), inp_n);
        inp_n = fmaf(win1, fmaf(NS, pn0.y, pu0.y), inp_n);
        inp_n = fmaf(win2, fmaf(NS, pn1.x, pu1.x), inp_n);
        inp_n = fmaf(win3, fmaf(NS, pn1.y, pu1.y), inp_n);
        inp_n = fmaf(win4, fmaf(NS, pn2.x, pu2.x), inp_n);
        inp_n = fmaf(win5, fmaf(NS, pn2.y, pu2.y), inp_n);
        inp_c = inp_n;
        rn_c  = rn_n;
        __syncthreads();
    }
    ob[(size_t)(T_ - 1) * N_ + n] = h;  // states[511]
}

extern "C" void kernel_launch(void* const* d_in, const int* in_sizes, int n_in,
                              void* d_out, int out_size, void* d_ws, size_t ws_size,
                              hipStream_t stream) {
    const float* u    = (const float*)d_in[0];
    const float* unz  = (const float*)d_in[1];
    const float* rnz  = (const float*)d_in[2];
    const float* Wrec = (const float*)d_in[3];
    const float* brec = (const float*)d_in[4];
    const float* Win  = (const float*)d_in[5];
    float* out = (float*)d_out;

    const size_t ws_need = (size_t)36 * N_ * sizeof(uint4);  // 294912 B
    if (ws_size >= ws_need) {
        uint4* ws = (uint4*)d_ws;
        prep_tail_kernel<<<(36 * N_ + 255) / 256, 256, 0, stream>>>(Wrec, ws);
        rnn_scan_kernel<true><<<dim3(B_), dim3(512), 0, stream>>>(
            u, unz, rnz, Wrec, brec, Win, ws, out);
    } else {
        rnn_scan_kernel<false><<<dim3(B_), dim3(512), 0, stream>>>(
            u, unz, rnz, Wrec, brec, Win, nullptr, out);
    }
}

// Round 8
// 1519.593 us; speedup vs baseline: 1.1683x; 1.1683x over previous
//
#include <hip/hip_runtime.h>

// RNN scan: h_{t+1} = 0.8*h_t + 0.2*(relu(h_t @ W_rec^T + b_rec + inp_t) + rn_t)
// 128 chains -> 128 blocks x 512 threads.  MFMA engine, R6 schedule (845us) +
// R8 owner-epilogue.
//
// R8: R7's cross-barrier pre-issue REGRESSED 2x (vmcnt(0)-before-barrier
// exposed the pre-loads; epilogue pu/pn consumed ~10 insts after issue).
// Reverted to R6's exact in-body stream schedule. New lever: since B is
// replicated across MFMA columns, EVERY lane holds the full D values
// (D col=lane&15, all equal) -> the h-update is done by fragment owners
// (lanes r16<4 own rows 64w+16*r16+4q+{0..3}, f32x4-contiguous):
//   - 'pre' LDS round-trip eliminated, ONE barrier/step instead of two
//   - 512-thread epilogue -> 16-owner-lanes/wave epilogue
//   - inp drive: Win/brec staged in LDS; u/unz (12 shared floats) loaded at
//     step start; inp computed mid-body on the idle VALU
//   - h state: 4 owner f32 regs (numerics unchanged); rn/out: owner float4
// PREDICT: dur 845 -> 600-690us, MfmaUtil 27.5 -> 33-40, LDS ~151552.
//
// Fragment layouts (verified R6):
//   A: lane l holds W[rowbase + (l&15)][32kk + 8*(l>>4) + e]  (e=0..7)
//   B: lane l holds h[32kk + 8*(l>>4) + e], identical for all 16 cols
//   D: col = l&15 (all equal), row = rowbase + 4*(l>>4) + r  (r=0..3)

#define B_  128
#define T_  512
#define N_  512
#define IN_ 6

typedef _Float16 f16x8 __attribute__((ext_vector_type(8)));
typedef float    f32x4 __attribute__((ext_vector_type(4)));
typedef _Float16 h2_t  __attribute__((ext_vector_type(2)));

union U4H8 { uint4 u; f16x8 h; };
__device__ __forceinline__ f16x8 h8(uint4 v) { U4H8 c; c.u = v; return c.h; }

// 8 consecutive fp32 -> 8 packed fp16 in a uint4
__device__ __forceinline__ uint4 pack8(const float* __restrict__ p) {
    const float4 f0 = ((const float4*)p)[0];
    const float4 f1 = ((const float4*)p)[1];
    union { unsigned u[4]; h2_t h[4]; } cv;
    cv.h[0] = h2_t{(_Float16)f0.x, (_Float16)f0.y};
    cv.h[1] = h2_t{(_Float16)f0.z, (_Float16)f0.w};
    cv.h[2] = h2_t{(_Float16)f1.x, (_Float16)f1.y};
    cv.h[3] = h2_t{(_Float16)f1.z, (_Float16)f1.w};
    return uint4{cv.u[0], cv.u[1], cv.u[2], cv.u[3]};
}

// opaque redefinition: blocks rematerialization of the producing load
#define KEEP4(v) asm volatile("" : "+v"((v).x), "+v"((v).y), "+v"((v).z), "+v"((v).w))

#define MFMA(A, Bv, C) __builtin_amdgcn_mfma_f32_16x16x32_f16(h8(A), h8(Bv), (C), 0, 0, 0)

// ---- prep: W_rec cols [224,512) -> fp16 image ws[g][n] = W[n][224+8g..+8] ----
__global__ void prep_tail_kernel(const float* __restrict__ Wrec,
                                 uint4* __restrict__ ws) {
    int tid = blockIdx.x * blockDim.x + threadIdx.x;
    if (tid >= 36 * N_) return;
    int g = tid >> 9, n = tid & (N_ - 1);
    ws[(size_t)g * N_ + n] = pack8(Wrec + (size_t)n * N_ + 224 + 8 * g);
}

// streamed A-frag (kk in 7..15): lane needs W[rowA+16T][32KK + 8q .. +8]
template <bool USE_WS>
__device__ __forceinline__ uint4 sld(const uint4* __restrict__ wsb,
                                     const float* __restrict__ Wrec,
                                     int rowA, int q, int KK, int T) {
    if constexpr (USE_WS) return wsb[2048 * (KK - 7) + 16 * T];
    else return pack8(Wrec + (size_t)(rowA + 16 * T) * N_ + 32 * KK + 8 * q);
}

template <bool USE_WS>
__global__ __launch_bounds__(512)
void rnn_scan_kernel(
    const float* __restrict__ u,     // [B,T,IN]
    const float* __restrict__ unz,   // [B,T,IN]
    const float* __restrict__ rnz,   // [B,T,N]
    const float* __restrict__ Wrec,  // [N,N]
    const float* __restrict__ brec,  // [N]
    const float* __restrict__ Win,   // [N,IN]
    const uint4* __restrict__ ws,    // fp16 tail image [36][N_]
    float* __restrict__ out)         // [B,T,N]
{
    const int b    = blockIdx.x;
    const int n    = threadIdx.x;
    const int w    = n >> 6;          // wave id: output rows 64w..64w+63
    const int lane = n & 63;
    const int q    = lane >> 4;       // k-subgroup
    const int r16  = lane & 15;       // A row-within-tile

    __shared__ uint4 lw[16 * N_];                    // 131072 B  (kk=3..6)
    __shared__ __align__(16) _Float16 hbuf[2][N_];   // 2048 B
    __shared__ __align__(16) float winl[N_ * 8];     // 16384 B (Win rows, pad 8)
    __shared__ __align__(16) float brl[N_];          // 2048 B   -> total 151552

    const int rowA = 64 * w + r16;
    const float* wp = Wrec + (size_t)rowA * N_ + 8 * q;  // + T*8192 + K*32

    // ---- one-time: A-frags kk=0..2 as 12 NAMED uint4 (48 VGPRs) ----
    uint4 a00 = pack8(wp +     0 +  0), a01 = pack8(wp +     0 + 32), a02 = pack8(wp +     0 + 64);
    uint4 a10 = pack8(wp +  8192 +  0), a11 = pack8(wp +  8192 + 32), a12 = pack8(wp +  8192 + 64);
    uint4 a20 = pack8(wp + 16384 +  0), a21 = pack8(wp + 16384 + 32), a22 = pack8(wp + 16384 + 64);
    uint4 a30 = pack8(wp + 24576 +  0), a31 = pack8(wp + 24576 + 32), a32 = pack8(wp + 24576 + 64);
    KEEP4(a00); KEEP4(a01); KEEP4(a02); KEEP4(a10); KEEP4(a11); KEEP4(a12);
    KEEP4(a20); KEEP4(a21); KEEP4(a22); KEEP4(a30); KEEP4(a31); KEEP4(a32);

    // ---- one-time: kk=3..6 into LDS: lw[j][m] = W[m][96+8j .. +8] ----
#pragma unroll
    for (int j = 0; j < 16; ++j)
        lw[j * N_ + n] = pack8(Wrec + (size_t)n * N_ + 96 + 8 * j);

    // ---- one-time: Win rows + brec into LDS ----
    winl[n * 8 + 0] = Win[n * IN_ + 0]; winl[n * 8 + 1] = Win[n * IN_ + 1];
    winl[n * 8 + 2] = Win[n * IN_ + 2]; winl[n * 8 + 3] = Win[n * IN_ + 3];
    winl[n * 8 + 4] = Win[n * IN_ + 4]; winl[n * 8 + 5] = Win[n * IN_ + 5];
    winl[n * 8 + 6] = 0.0f;             winl[n * 8 + 7] = 0.0f;
    brl[n] = brec[n];

    const float NS = 0.6324555320336759f;  // sqrt(2/alpha * sigma^2)

    float* ob = out + (size_t)b * T_ * N_;
    const float* rb = rnz + (size_t)b * T_ * N_;
    const float2* ubp = (const float2*)(u   + (size_t)b * T_ * IN_);
    const float2* nbp = (const float2*)(unz + (size_t)b * T_ * IN_);

    const uint4* wsb = nullptr;
    if constexpr (USE_WS) wsb = ws + (size_t)q * N_ + 64 * w + r16;
    const int lbase = q * N_ + 64 * w + r16;   // lw read base (kk=3, T=0)
    const uint4* hb0 = (const uint4*)&hbuf[0][0];
    const uint4* hb1 = (const uint4*)&hbuf[1][0];

    // owner: lanes r16<4 own rows rowO..rowO+3 (tile T = r16)
    const bool owner = (r16 < 4);
    const int rowO = 64 * w + 16 * r16 + 4 * q;
    float h0 = 0.0f, h1 = 0.0f, h2 = 0.0f, h3 = 0.0f;   // owner h-state (f32)

    hbuf[0][n] = (_Float16)0.0f;
    hbuf[1][n] = (_Float16)0.0f;
    ob[n] = 0.0f;                      // states[0] = zeros
    __syncthreads();

#pragma unroll 1
    for (int t = 0; t < T_ - 1; ++t) {
        const uint4* hb = (t & 1) ? hb1 : hb0;          // B source (h_t, fp16)

        // B frag kk: hb[4*kk + q] = h[32kk + 8q .. +8]
        uint4 bf0 = hb[q], bf1 = hb[4 + q];

        // stream prologue: kk=7,8 in flight (2-deep window)  [R6 verbatim]
        uint4 sa0 = sld<USE_WS>(wsb, Wrec, rowA, q, 7, 0), sa1 = sld<USE_WS>(wsb, Wrec, rowA, q, 7, 1),
              sa2 = sld<USE_WS>(wsb, Wrec, rowA, q, 7, 2), sa3 = sld<USE_WS>(wsb, Wrec, rowA, q, 7, 3);
        uint4 sb0 = sld<USE_WS>(wsb, Wrec, rowA, q, 8, 0), sb1 = sld<USE_WS>(wsb, Wrec, rowA, q, 8, 1),
              sb2 = sld<USE_WS>(wsb, Wrec, rowA, q, 8, 2), sb3 = sld<USE_WS>(wsb, Wrec, rowA, q, 8, 3);

        // owner inputs for step t (consumed at the end-of-step update)
        float4 rn4{0,0,0,0};
        float2 uu0{0,0}, uu1{0,0}, uu2{0,0}, nu0{0,0}, nu1{0,0}, nu2{0,0};
        if (owner) {
            rn4 = *(const float4*)(rb + (size_t)t * N_ + rowO);
            uu0 = ubp[t * 3 + 0]; uu1 = ubp[t * 3 + 1]; uu2 = ubp[t * 3 + 2];
            nu0 = nbp[t * 3 + 0]; nu1 = nbp[t * 3 + 1]; nu2 = nbp[t * 3 + 2];
        }

        const f32x4 zz = {0.0f, 0.0f, 0.0f, 0.0f};

        // ---- kk=0..2 from registers ----
        uint4 bf2 = hb[8 + q];
        f32x4 d0 = MFMA(a00, bf0, zz), d1 = MFMA(a10, bf0, zz),
              d2 = MFMA(a20, bf0, zz), d3 = MFMA(a30, bf0, zz);
        uint4 bf3 = hb[12 + q];
        d0 = MFMA(a01, bf1, d0); d1 = MFMA(a11, bf1, d1);
        d2 = MFMA(a21, bf1, d2); d3 = MFMA(a31, bf1, d3);
        uint4 bf4 = hb[16 + q];
        d0 = MFMA(a02, bf2, d0); d1 = MFMA(a12, bf2, d1);
        d2 = MFMA(a22, bf2, d2); d3 = MFMA(a32, bf2, d3);

        // owner inp drive: computed here, on the idle VALU, off the tail path
        float i0 = 0.0f, i1 = 0.0f, i2 = 0.0f, i3 = 0.0f;
        if (owner) {
            const float c0 = fmaf(NS, nu0.x, uu0.x), c1 = fmaf(NS, nu0.y, uu0.y);
            const float c2 = fmaf(NS, nu1.x, uu1.x), c3 = fmaf(NS, nu1.y, uu1.y);
            const float c4 = fmaf(NS, nu2.x, uu2.x), c5 = fmaf(NS, nu2.y, uu2.y);
            const float4 b4 = *(const float4*)&brl[rowO];
#pragma unroll
            for (int r = 0; r < 4; ++r) {
                const float4 wA = *(const float4*)&winl[(rowO + r) * 8];
                const float2 wB = *(const float2*)&winl[(rowO + r) * 8 + 4];
                float v = (r == 0) ? b4.x : (r == 1) ? b4.y : (r == 2) ? b4.z : b4.w;
                v = fmaf(wA.x, c0, v); v = fmaf(wA.y, c1, v); v = fmaf(wA.z, c2, v);
                v = fmaf(wA.w, c3, v); v = fmaf(wB.x, c4, v); v = fmaf(wB.y, c5, v);
                if (r == 0) i0 = v; else if (r == 1) i1 = v; else if (r == 2) i2 = v; else i3 = v;
            }
        }

        // ---- kk=3..6 from LDS ----
        uint4 l30 = lw[lbase + 0], l31 = lw[lbase + 16], l32 = lw[lbase + 32], l33 = lw[lbase + 48];
        uint4 bf5 = hb[20 + q];
        d0 = MFMA(l30, bf3, d0); d1 = MFMA(l31, bf3, d1);
        d2 = MFMA(l32, bf3, d2); d3 = MFMA(l33, bf3, d3);
        uint4 l40 = lw[lbase + 2048], l41 = lw[lbase + 2064], l42 = lw[lbase + 2080], l43 = lw[lbase + 2096];
        uint4 bf6 = hb[24 + q];
        d0 = MFMA(l40, bf4, d0); d1 = MFMA(l41, bf4, d1);
        d2 = MFMA(l42, bf4, d2); d3 = MFMA(l43, bf4, d3);
        uint4 l50 = lw[lbase + 4096], l51 = lw[lbase + 4112], l52 = lw[lbase + 4128], l53 = lw[lbase + 4144];
        uint4 bf7 = hb[28 + q];
        d0 = MFMA(l50, bf5, d0); d1 = MFMA(l51, bf5, d1);
        d2 = MFMA(l52, bf5, d2); d3 = MFMA(l53, bf5, d3);
        uint4 l60 = lw[lbase + 6144], l61 = lw[lbase + 6160], l62 = lw[lbase + 6176], l63 = lw[lbase + 6192];
        uint4 bf8 = hb[32 + q];
        d0 = MFMA(l60, bf6, d0); d1 = MFMA(l61, bf6, d1);
        d2 = MFMA(l62, bf6, d2); d3 = MFMA(l63, bf6, d3);

        // ---- kk=7..15 streamed, 2-deep rotating window  [R6 verbatim] ----
        uint4 bf9 = hb[36 + q];
        d0 = MFMA(sa0, bf7, d0); d1 = MFMA(sa1, bf7, d1);
        d2 = MFMA(sa2, bf7, d2); d3 = MFMA(sa3, bf7, d3);
        sa0 = sld<USE_WS>(wsb, Wrec, rowA, q, 9, 0); sa1 = sld<USE_WS>(wsb, Wrec, rowA, q, 9, 1);
        sa2 = sld<USE_WS>(wsb, Wrec, rowA, q, 9, 2); sa3 = sld<USE_WS>(wsb, Wrec, rowA, q, 9, 3);

        uint4 bf10 = hb[40 + q];
        d0 = MFMA(sb0, bf8, d0); d1 = MFMA(sb1, bf8, d1);
        d2 = MFMA(sb2, bf8, d2); d3 = MFMA(sb3, bf8, d3);
        sb0 = sld<USE_WS>(wsb, Wrec, rowA, q, 10, 0); sb1 = sld<USE_WS>(wsb, Wrec, rowA, q, 10, 1);
        sb2 = sld<USE_WS>(wsb, Wrec, rowA, q, 10, 2); sb3 = sld<USE_WS>(wsb, Wrec, rowA, q, 10, 3);

        uint4 bf11 = hb[44 + q];
        d0 = MFMA(sa0, bf9, d0); d1 = MFMA(sa1, bf9, d1);
        d2 = MFMA(sa2, bf9, d2); d3 = MFMA(sa3, bf9, d3);
        sa0 = sld<USE_WS>(wsb, Wrec, rowA, q, 11, 0); sa1 = sld<USE_WS>(wsb, Wrec, rowA, q, 11, 1);
        sa2 = sld<USE_WS>(wsb, Wrec, rowA, q, 11, 2); sa3 = sld<USE_WS>(wsb, Wrec, rowA, q, 11, 3);

        uint4 bf12 = hb[48 + q];
        d0 = MFMA(sb0, bf10, d0); d1 = MFMA(sb1, bf10, d1);
        d2 = MFMA(sb2, bf10, d2); d3 = MFMA(sb3, bf10, d3);
        sb0 = sld<USE_WS>(wsb, Wrec, rowA, q, 12, 0); sb1 = sld<USE_WS>(wsb, Wrec, rowA, q, 12, 1);
        sb2 = sld<USE_WS>(wsb, Wrec, rowA, q, 12, 2); sb3 = sld<USE_WS>(wsb, Wrec, rowA, q, 12, 3);

        uint4 bf13 = hb[52 + q];
        d0 = MFMA(sa0, bf11, d0); d1 = MFMA(sa1, bf11, d1);
        d2 = MFMA(sa2, bf11, d2); d3 = MFMA(sa3, bf11, d3);
        sa0 = sld<USE_WS>(wsb, Wrec, rowA, q, 13, 0); sa1 = sld<USE_WS>(wsb, Wrec, rowA, q, 13, 1);
        sa2 = sld<USE_WS>(wsb, Wrec, rowA, q, 13, 2); sa3 = sld<USE_WS>(wsb, Wrec, rowA, q, 13, 3);

        uint4 bf14 = hb[56 + q];
        d0 = MFMA(sb0, bf12, d0); d1 = MFMA(sb1, bf12, d1);
        d2 = MFMA(sb2, bf12, d2); d3 = MFMA(sb3, bf12, d3);
        sb0 = sld<USE_WS>(wsb, Wrec, rowA, q, 14, 0); sb1 = sld<USE_WS>(wsb, Wrec, rowA, q, 14, 1);
        sb2 = sld<USE_WS>(wsb, Wrec, rowA, q, 14, 2); sb3 = sld<USE_WS>(wsb, Wrec, rowA, q, 14, 3);

        uint4 bf15 = hb[60 + q];
        d0 = MFMA(sa0, bf13, d0); d1 = MFMA(sa1, bf13, d1);
        d2 = MFMA(sa2, bf13, d2); d3 = MFMA(sa3, bf13, d3);
        sa0 = sld<USE_WS>(wsb, Wrec, rowA, q, 15, 0); sa1 = sld<USE_WS>(wsb, Wrec, rowA, q, 15, 1);
        sa2 = sld<USE_WS>(wsb, Wrec, rowA, q, 15, 2); sa3 = sld<USE_WS>(wsb, Wrec, rowA, q, 15, 3);

        d0 = MFMA(sb0, bf14, d0); d1 = MFMA(sb1, bf14, d1);
        d2 = MFMA(sb2, bf14, d2); d3 = MFMA(sb3, bf14, d3);

        d0 = MFMA(sa0, bf15, d0); d1 = MFMA(sa1, bf15, d1);
        d2 = MFMA(sa2, bf15, d2); d3 = MFMA(sa3, bf15, d3);

        // ---- owner epilogue: in-register h-update for rows rowO..rowO+3 ----
        if (owner) {
            // every lane's D columns are identical -> select own tile (T=r16)
            const f32x4 dd = (r16 == 0) ? d0 : (r16 == 1) ? d1 : (r16 == 2) ? d2 : d3;
            h0 = 0.8f * h0 + 0.2f * (fmaxf(dd[0] + i0, 0.0f) + rn4.x);
            h1 = 0.8f * h1 + 0.2f * (fmaxf(dd[1] + i1, 0.0f) + rn4.y);
            h2 = 0.8f * h2 + 0.2f * (fmaxf(dd[2] + i2, 0.0f) + rn4.z);
            h3 = 0.8f * h3 + 0.2f * (fmaxf(dd[3] + i3, 0.0f) + rn4.w);
            // states[t+1]
            *(float4*)(ob + (size_t)(t + 1) * N_ + rowO) = float4{h0, h1, h2, h3};
            // h_{t+1} fp16 -> hbuf[(t+1)&1]
            union { uint2 u2; h2_t h[2]; } pk;
            pk.h[0] = h2_t{(_Float16)h0, (_Float16)h1};
            pk.h[1] = h2_t{(_Float16)h2, (_Float16)h3};
            *(uint2*)(&hbuf[(t + 1) & 1][rowO]) = pk.u2;
        }
        __syncthreads();
    }
}

extern "C" void kernel_launch(void* const* d_in, const int* in_sizes, int n_in,
                              void* d_out, int out_size, void* d_ws, size_t ws_size,
                              hipStream_t stream) {
    const float* u    = (const float*)d_in[0];
    const float* unz  = (const float*)d_in[1];
    const float* rnz  = (const float*)d_in[2];
    const float* Wrec = (const float*)d_in[3];
    const float* brec = (const float*)d_in[4];
    const float* Win  = (const float*)d_in[5];
    float* out = (float*)d_out;

    const size_t ws_need = (size_t)36 * N_ * sizeof(uint4);  // 294912 B
    if (ws_size >= ws_need) {
        uint4* ws = (uint4*)d_ws;
        prep_tail_kernel<<<(36 * N_ + 255) / 256, 256, 0, stream>>>(Wrec, ws);
        rnn_scan_kernel<true><<<dim3(B_), dim3(512), 0, stream>>>(
            u, unz, rnz, Wrec, brec, Win, ws, out);
    } else {
        rnn_scan_kernel<false><<<dim3(B_), dim3(512), 0, stream>>>(
            u, unz, rnz, Wrec, brec, Win, nullptr, out);
    }
}